// Round 5
// baseline (933.165 us; speedup 1.0000x reference)
//
#include <hip/hip_runtime.h>

#define KK 27
#define EPSV 1e-5f
#define KS_NB 128

typedef __attribute__((ext_vector_type(8))) short bf16x8;
typedef __attribute__((ext_vector_type(4))) float f32x4;
typedef __attribute__((ext_vector_type(4))) unsigned int u32x4;

static __device__ __forceinline__ unsigned short f2bf(float f) {
    unsigned u = __float_as_uint(f);
    u = u + 0x7fffu + ((u >> 16) & 1u);
    return (unsigned short)(u >> 16);
}

// f16 helpers (v_cvt_f16_f32 / v_cvt_f32_f16, SDWA hi/lo selects fold the shift)
static __device__ __forceinline__ unsigned short f2h(float f) {
    _Float16 h = (_Float16)f;
    unsigned short u;
    __builtin_memcpy(&u, &h, 2);
    return u;
}
static __device__ __forceinline__ float h2f(unsigned short s) {
    _Float16 h;
    __builtin_memcpy(&h, &s, 2);
    return (float)h;
}
static __device__ __forceinline__ float hlo(unsigned u) { return h2f((unsigned short)(u & 0xffffu)); }
static __device__ __forceinline__ float hhi(unsigned u) { return h2f((unsigned short)(u >> 16)); }

// --- K0: transpose+convert W1[m][k][n] (fp32) -> WT[m][n][k] (bf16, MFMA operand) ---
__global__ void k0_wt(const float* __restrict__ W1, unsigned short* __restrict__ WT) {
    int m = blockIdx.x >> 7, n = blockIdx.x & 127, k = threadIdx.x;
    WT[((m * 128 + n) * 128) + k] = f2bf(W1[(m * 128 + k) * 128 + n]);
}

// --- KS: XtX partial slabs + colsum.  XtX = x^T x (128x128), computed per-block
//     into register acc across grid-strided 64-row chunks, plain-stored to slab
//     blockIdx (no atomics). colsum accumulated per-thread then LDS-reduced.
__launch_bounds__(256)
__global__ void kS_xtx(const float* __restrict__ x, float* __restrict__ slabs,
                       float* __restrict__ colsum, int N, int nchunk) {
    __shared__ unsigned short AsT[128 * 68];   // [ch][vox], stride 68 (2-way-conflict max)
    __shared__ float csL[8 * 128];
    const int t = threadIdx.x;
    const int w = t >> 6, lane = t & 63;
    const int r16 = lane & 15, q = lane >> 4;
    const int c4 = (t & 31) * 4;

    f32x4 acc[2][8];
#pragma unroll
    for (int ri = 0; ri < 2; ++ri)
#pragma unroll
        for (int b = 0; b < 8; ++b) { acc[ri][b][0]=0.f; acc[ri][b][1]=0.f; acc[ri][b][2]=0.f; acc[ri][b][3]=0.f; }

    float cs0 = 0.f, cs1 = 0.f, cs2 = 0.f, cs3 = 0.f;

    for (int ch = blockIdx.x; ch < nchunk; ch += KS_NB) {
        const int i0 = ch * 64;
        __syncthreads();
#pragma unroll
        for (int it = 0; it < 8; ++it) {
            int r = it * 8 + (t >> 5);
            float4 v = make_float4(0.f, 0.f, 0.f, 0.f);
            if (i0 + r < N) v = *(const float4*)(x + (size_t)(i0 + r) * 128 + c4);
            AsT[(c4 + 0) * 68 + r] = f2bf(v.x);
            AsT[(c4 + 1) * 68 + r] = f2bf(v.y);
            AsT[(c4 + 2) * 68 + r] = f2bf(v.z);
            AsT[(c4 + 3) * 68 + r] = f2bf(v.w);
            cs0 += v.x; cs1 += v.y; cs2 += v.z; cs3 += v.w;
        }
        __syncthreads();
#pragma unroll
        for (int kc = 0; kc < 2; ++kc) {
            bf16x8 f[8];
#pragma unroll
            for (int i = 0; i < 8; ++i)
                f[i] = *(const bf16x8*)(AsT + (i * 16 + r16) * 68 + kc * 32 + q * 8);
#pragma unroll
            for (int ri = 0; ri < 2; ++ri)
#pragma unroll
                for (int b = 0; b < 8; ++b)
                    acc[ri][b] = __builtin_amdgcn_mfma_f32_16x16x32_bf16(f[w * 2 + ri], f[b], acc[ri][b], 0, 0, 0);
        }
    }

    // slab store (plain, no atomics): XtX[row][col] partial for this block
    float* slab = slabs + (size_t)blockIdx.x * 16384;
#pragma unroll
    for (int ri = 0; ri < 2; ++ri)
#pragma unroll
        for (int b = 0; b < 8; ++b)
#pragma unroll
            for (int r = 0; r < 4; ++r) {
                int row = (w * 2 + ri) * 16 + q * 4 + r;
                int col = b * 16 + r16;
                slab[row * 128 + col] = acc[ri][b][r];
            }

    // colsum: thread's channel set is fixed (c4..c4+3); reduce 8 contributors/channel
    __syncthreads();
    csL[(t >> 5) * 128 + c4 + 0] = cs0;
    csL[(t >> 5) * 128 + c4 + 1] = cs1;
    csL[(t >> 5) * 128 + c4 + 2] = cs2;
    csL[(t >> 5) * 128 + c4 + 3] = cs3;
    __syncthreads();
    if (t < 128) {
        float s = 0.f;
#pragma unroll
        for (int g = 0; g < 8; ++g) s += csL[g * 128 + t];
        atomicAdd(colsum + t, s);
    }
}

// --- KR: reduce XtX slabs -> final XtX (coalesced) ---
__global__ void kR_reduce(const float* __restrict__ slabs, float* __restrict__ XtX, int nslab) {
    int t = blockIdx.x * blockDim.x + threadIdx.x;   // 16384 total
    float s = 0.f;
    for (int sl = 0; sl < nslab; ++sl) s += slabs[(size_t)sl * 16384 + t];
    XtX[t] = s;
}

// --- K2B: analytic BN1 coefs. One block per (m,c):
//     mean = (colsum . w)/N ; E[y^2] = w^T XtX w / N ; w = W1[m][:,c]
__launch_bounds__(256)
__global__ void k2b_coef(const float* __restrict__ XtX, const float* __restrict__ colsum,
                         const float* __restrict__ W1, const float* __restrict__ g1,
                         const float* __restrict__ b1, float* __restrict__ a1,
                         float* __restrict__ c1, int N) {
    const int mc = blockIdx.x, m = mc >> 7, c = mc & 127;
    __shared__ float wS[128];
    __shared__ float red[8];
    const int t = threadIdx.x;
    if (t < 128) wS[t] = W1[(m * 128 + t) * 128 + c];
    __syncthreads();
    const int a = t >> 1, b0 = (t & 1) * 64;
    float s = 0.f;
    for (int i = 0; i < 64; ++i) s += XtX[a * 128 + b0 + i] * wS[b0 + i];
    s *= wS[a];
    float mp = (t < 128) ? colsum[t] * wS[t] : 0.f;
#pragma unroll
    for (int d = 1; d < 64; d <<= 1) { s += __shfl_xor(s, d); mp += __shfl_xor(mp, d); }
    if ((t & 63) == 0) { red[t >> 6] = s; red[4 + (t >> 6)] = mp; }
    __syncthreads();
    if (t == 0) {
        float sy2 = red[0] + red[1] + red[2] + red[3];
        float my  = red[4] + red[5] + red[6] + red[7];
        float mean = my / (float)N;
        float var  = sy2 / (float)N - mean * mean;
        float aa = g1[mc] * rsqrtf(var + EPSV);
        a1[mc] = aa;
        c1[mc] = b1[mc] - mean * aa;
    }
}

// --- KA: y_m = x @ W1[m] for m in [m0,m1); Yall[row][(m-m0)*128 + c] f16 raw (pre-BN)
//     STATS=0 (fused): pure GEMM+store, no atomics. STATS=1 (fallback): ysum/ysq.
template <int STATS>
__launch_bounds__(256)
__global__ void kA_gemm(const float* __restrict__ x, const unsigned short* __restrict__ WT,
                        unsigned short* __restrict__ Yall, float* __restrict__ ysum,
                        float* __restrict__ ysq,
                        int N, int m0, int m1, int ystride) {
    __shared__ unsigned short As[64 * 136];   // [row][k], pad 8
    __shared__ unsigned short Bs[128 * 136];  // [n][k], pad 8; reused as Ys tile per m
    const int t = threadIdx.x;
    const int i0 = blockIdx.x * 64;

#pragma unroll
    for (int it = 0; it < 8; ++it) {
        int flat = it * 256 + t;
        int r = flat >> 5, c4 = (flat & 31) * 4;
        float4 v = make_float4(0.f, 0.f, 0.f, 0.f);
        if (i0 + r < N) v = *(const float4*)(x + (size_t)(i0 + r) * 128 + c4);
        ushort4 bb;
        bb.x = f2bf(v.x); bb.y = f2bf(v.y); bb.z = f2bf(v.z); bb.w = f2bf(v.w);
        *(ushort4*)(As + r * 136 + c4) = bb;
    }

    const int w = t >> 6, lane = t & 63;
    const int wr = w >> 1, wc = w & 1;
    const int r16 = lane & 15, q = lane >> 4;

    for (int m = m0; m < m1; ++m) {
        __syncthreads();
        const uint4* Wp = (const uint4*)(WT + (size_t)m * 128 * 128);
#pragma unroll
        for (int it = 0; it < 8; ++it) {
            int flat = it * 256 + t;
            int n = flat >> 4, kc = flat & 15;
            uint4 v = Wp[n * 16 + kc];
            *(uint4*)(Bs + n * 136 + kc * 8) = v;
        }
        __syncthreads();

        f32x4 acc[2][4];
#pragma unroll
        for (int a = 0; a < 2; ++a)
#pragma unroll
            for (int b = 0; b < 4; ++b) { acc[a][b][0] = 0.f; acc[a][b][1] = 0.f; acc[a][b][2] = 0.f; acc[a][b][3] = 0.f; }

#pragma unroll
        for (int ks = 0; ks < 4; ++ks) {
            int ko = ks * 32 + q * 8;
            bf16x8 af[2], bfr[4];
#pragma unroll
            for (int ri = 0; ri < 2; ++ri)
                af[ri] = *(const bf16x8*)(As + (wr * 32 + ri * 16 + r16) * 136 + ko);
#pragma unroll
            for (int ci = 0; ci < 4; ++ci)
                bfr[ci] = *(const bf16x8*)(Bs + (wc * 64 + ci * 16 + r16) * 136 + ko);
#pragma unroll
            for (int ri = 0; ri < 2; ++ri)
#pragma unroll
                for (int ci = 0; ci < 4; ++ci)
                    acc[ri][ci] = __builtin_amdgcn_mfma_f32_16x16x32_bf16(af[ri], bfr[ci], acc[ri][ci], 0, 0, 0);
        }

        if (STATS) {
#pragma unroll
            for (int ci = 0; ci < 4; ++ci) {
                float s = 0.f, s2 = 0.f;
#pragma unroll
                for (int ri = 0; ri < 2; ++ri) {
#pragma unroll
                    for (int r = 0; r < 4; ++r) {
                        int row = i0 + wr * 32 + ri * 16 + q * 4 + r;
                        float vv = acc[ri][ci][r];
                        if (row < N) { s += vv; s2 += vv * vv; }
                    }
                }
                s  += __shfl_xor(s, 16);  s  += __shfl_xor(s, 32);
                s2 += __shfl_xor(s2, 16); s2 += __shfl_xor(s2, 32);
                if (lane < 16) {
                    int col = wc * 64 + ci * 16 + r16;
                    atomicAdd(ysum + m * 128 + col, s);
                    atomicAdd(ysq  + m * 128 + col, s2);
                }
            }
        }

        __syncthreads();
        unsigned short* Ys = Bs;
#pragma unroll
        for (int ci = 0; ci < 4; ++ci) {
            int col = wc * 64 + ci * 16 + r16;
#pragma unroll
            for (int ri = 0; ri < 2; ++ri) {
#pragma unroll
                for (int r = 0; r < 4; ++r) {
                    int rl = wr * 32 + ri * 16 + q * 4 + r;
                    Ys[rl * 136 + col] = f2h(acc[ri][ci][r]);
                }
            }
        }
        __syncthreads();
        const int cb = (m - m0) * 128;
#pragma unroll
        for (int it = 0; it < 4; ++it) {
            int chunk = it * 256 + t;
            int row = chunk >> 4, c8 = (chunk & 15) * 8;
            if (i0 + row < N) {
                u32x4 v = *(const u32x4*)(Ys + row * 136 + c8);
                __builtin_nontemporal_store(v, (u32x4*)(Yall + (size_t)(i0 + row) * ystride + cb + c8));
            }
        }
    }
}

// --- K2: fallback BN1 coef finalize (single-bin stats) ---
__global__ void k2_coef(const float* __restrict__ ysum, const float* __restrict__ ysq,
                        const float* __restrict__ g1, const float* __restrict__ b1,
                        float* __restrict__ a1, float* __restrict__ c1, int N, int m0) {
    int c = threadIdx.x & 127;
    int m = m0 + (threadIdx.x >> 7);
    float mean = ysum[m * 128 + c] / (float)N;
    float var  = ysq[m * 128 + c] / (float)N - mean * mean;
    float a = g1[m * 128 + c] * rsqrtf(var + EPSV);
    a1[m * 128 + c] = a;
    c1[m * 128 + c] = b1[m * 128 + c] - mean * a;
}

// --- K4_ALL: gather with inline BN+ReLU. 4 voxels per wave (quad q owns v0+q).
//     Grid 2048 (empirically best; 1280 "exact residency" regressed). Output
//     stats binned 4x.
__launch_bounds__(256)
__global__ void k4_all(const unsigned short* __restrict__ Y, const int* __restrict__ nbr,
                       const float* __restrict__ wkg, const float* __restrict__ A1g,
                       const float* __restrict__ C1g, float* __restrict__ P,
                       float* __restrict__ osum_b, float* __restrict__ osq_b, int N) {
    __shared__ unsigned short wkL[4 * KK * 136];   // f16 [m*27+k][c] pad 8
    __shared__ float ssum[128], ssq[128];
    const int t = threadIdx.x;
    for (int idx = t; idx < 4 * KK * 128; idx += 256) {
        int c = idx & 127, km = idx >> 7;          // km = m*27+k (c inner)
        wkL[km * 136 + c] = f2h(wkg[idx]);
    }
    if (t < 128) { ssum[t] = 0.f; ssq[t] = 0.f; }

    const int lane = t & 63;
    const int m = lane >> 4, c16 = lane & 15;
    const int q = m;
    const unsigned short* wbase = wkL + (m * KK) * 136 + c16 * 8;
    const unsigned short* hbase = Y + lane * 8;

    // BN coefficients for THIS lane's branch m, channels c16*8..+8
    float Ar[8], Cr[8];
    {
        const float4 A0 = *(const float4*)(A1g + m * 128 + c16 * 8);
        const float4 A1 = *(const float4*)(A1g + m * 128 + c16 * 8 + 4);
        const float4 C0 = *(const float4*)(C1g + m * 128 + c16 * 8);
        const float4 C1 = *(const float4*)(C1g + m * 128 + c16 * 8 + 4);
        Ar[0]=A0.x; Ar[1]=A0.y; Ar[2]=A0.z; Ar[3]=A0.w;
        Ar[4]=A1.x; Ar[5]=A1.y; Ar[6]=A1.z; Ar[7]=A1.w;
        Cr[0]=C0.x; Cr[1]=C0.y; Cr[2]=C0.z; Cr[3]=C0.w;
        Cr[4]=C1.x; Cr[5]=C1.y; Cr[6]=C1.z; Cr[7]=C1.w;
    }
    __syncthreads();

    float os[8], oq[8];
#pragma unroll
    for (int e = 0; e < 8; ++e) { os[e] = 0.f; oq[e] = 0.f; }

    const int wid = blockIdx.x * 4 + (t >> 6);
    const int nw  = gridDim.x * 4;
    const int ng  = (N + 3) >> 2;
    for (int vg = wid; vg < ng; vg += nw) {
        const int v0 = __builtin_amdgcn_readfirstlane(vg << 2);
        const int* np = nbr + (size_t)v0 * KK;     // wave-uniform -> s_load
        const int o1 = (v0 + 1 < N) ? KK : 0;      // clamp tail rows (replay row 0)
        const int o2 = (v0 + 2 < N) ? 2 * KK : 0;
        const int o3 = (v0 + 3 < N) ? 3 * KK : 0;
        float acc0[8], acc1[8], acc2[8], acc3[8];
#pragma unroll
        for (int e = 0; e < 8; ++e) { acc0[e] = 0.f; acc1[e] = 0.f; acc2[e] = 0.f; acc3[e] = 0.f; }

#pragma unroll 3
        for (int k = 0; k < KK; ++k) {
            const int j0 = np[k];
            const int j1 = np[o1 + k];
            const int j2 = np[o2 + k];
            const int j3 = np[o3 + k];
            // whole wave loads each full 1KB interleaved row: lane*16B
            const uint4 hv0 = *(const uint4*)(hbase + ((size_t)j0 << 9));
            const uint4 hv1 = *(const uint4*)(hbase + ((size_t)j1 << 9));
            const uint4 hv2 = *(const uint4*)(hbase + ((size_t)j2 << 9));
            const uint4 hv3 = *(const uint4*)(hbase + ((size_t)j3 << 9));
            const uint4 wv  = *(const uint4*)(wbase + k * 136);
            const float w0 = hlo(wv.x), w1 = hhi(wv.x), w2 = hlo(wv.y), w3 = hhi(wv.y);
            const float w4 = hlo(wv.z), w5 = hhi(wv.z), w6 = hlo(wv.w), w7 = hhi(wv.w);
#define K4BODY(A, H)                                                        \
            A[0] += fmaxf(0.f, hlo(H.x) * Ar[0] + Cr[0]) * w0;              \
            A[1] += fmaxf(0.f, hhi(H.x) * Ar[1] + Cr[1]) * w1;              \
            A[2] += fmaxf(0.f, hlo(H.y) * Ar[2] + Cr[2]) * w2;              \
            A[3] += fmaxf(0.f, hhi(H.y) * Ar[3] + Cr[3]) * w3;              \
            A[4] += fmaxf(0.f, hlo(H.z) * Ar[4] + Cr[4]) * w4;              \
            A[5] += fmaxf(0.f, hhi(H.z) * Ar[5] + Cr[5]) * w5;              \
            A[6] += fmaxf(0.f, hlo(H.w) * Ar[6] + Cr[6]) * w6;              \
            A[7] += fmaxf(0.f, hhi(H.w) * Ar[7] + Cr[7]) * w7;
            K4BODY(acc0, hv0)
            K4BODY(acc1, hv1)
            K4BODY(acc2, hv2)
            K4BODY(acc3, hv3)
#undef K4BODY
        }

        // sum over the 4 branches (quads): lanes {l, l^16, l^32, l^48}
#pragma unroll
        for (int e = 0; e < 8; ++e) {
            acc0[e] += __shfl_xor(acc0[e], 16); acc0[e] += __shfl_xor(acc0[e], 32);
            acc1[e] += __shfl_xor(acc1[e], 16); acc1[e] += __shfl_xor(acc1[e], 32);
            acc2[e] += __shfl_xor(acc2[e], 16); acc2[e] += __shfl_xor(acc2[e], 32);
            acc3[e] += __shfl_xor(acc3[e], 16); acc3[e] += __shfl_xor(acc3[e], 32);
        }
        // quad q owns voxel v0+q (static select — no runtime array index)
        float av[8];
#pragma unroll
        for (int e = 0; e < 8; ++e)
            av[e] = (q == 0) ? acc0[e] : (q == 1) ? acc1[e] : (q == 2) ? acc2[e] : acc3[e];
        const int vq = v0 + q;
        if (vq < N) {
            f32x4 x0 = {av[0], av[1], av[2], av[3]};
            f32x4 x1 = {av[4], av[5], av[6], av[7]};
            float* p = P + (size_t)vq * 128 + c16 * 8;
            __builtin_nontemporal_store(x0, (f32x4*)p);
            __builtin_nontemporal_store(x1, (f32x4*)(p + 4));
#pragma unroll
            for (int e = 0; e < 8; ++e) { os[e] += av[e]; oq[e] += av[e] * av[e]; }
        }
    }

    // every lane contributes its quad's voxel stats (LDS pre-reduce, then binned global)
#pragma unroll
    for (int e = 0; e < 8; ++e) {
        atomicAdd(ssum + c16 * 8 + e, os[e]);
        atomicAdd(ssq  + c16 * 8 + e, oq[e]);
    }
    __syncthreads();
    if (t < 128) {
        const int bo = (blockIdx.x & 3) * 128;
        atomicAdd(osum_b + bo + t, ssum[t]);
        atomicAdd(osq_b  + bo + t, ssq[t]);
    }
}

// --- K4 fallback (per-branch, compact Y, BN inline; Y is f16) ---
template <int MODE>
__launch_bounds__(256)
__global__ void k4_gather(const unsigned short* __restrict__ Ym, int ystride,
                          const int* __restrict__ nbr,
                          const float* __restrict__ wkm, const float* __restrict__ a1m,
                          const float* __restrict__ c1m, float* __restrict__ P,
                          float* __restrict__ osum, float* __restrict__ osq, int N) {
    __shared__ float wkL[KK * 132];
    __shared__ float ssum[128], ssq[128];
    const int t = threadIdx.x;
    for (int idx = t; idx < KK * 128; idx += 256) {
        int k = idx >> 7, c = idx & 127;
        wkL[k * 132 + c] = wkm[k * 128 + c];
    }
    if (MODE == 2) { if (t < 128) { ssum[t] = 0.f; ssq[t] = 0.f; } }

    const int w = t >> 6, lane = t & 63;
    const int q = lane >> 4, c16 = lane & 15;
    const int slot = w * 4 + q;
    const int vox = blockIdx.x * 16 + slot;
    const bool alive = vox < N;

    float aR[8], cR[8];
    {
        const float4 A0 = *(const float4*)(a1m + c16 * 8);
        const float4 A1 = *(const float4*)(a1m + c16 * 8 + 4);
        const float4 C0 = *(const float4*)(c1m + c16 * 8);
        const float4 C1 = *(const float4*)(c1m + c16 * 8 + 4);
        aR[0]=A0.x; aR[1]=A0.y; aR[2]=A0.z; aR[3]=A0.w;
        aR[4]=A1.x; aR[5]=A1.y; aR[6]=A1.z; aR[7]=A1.w;
        cR[0]=C0.x; cR[1]=C0.y; cR[2]=C0.z; cR[3]=C0.w;
        cR[4]=C1.x; cR[5]=C1.y; cR[6]=C1.z; cR[7]=C1.w;
    }
    __syncthreads();

    const long long base = alive ? (long long)vox * KK : 0;
    float acc[8];
#pragma unroll
    for (int e = 0; e < 8; ++e) acc[e] = 0.f;

#pragma unroll 3
    for (int k = 0; k < KK; ++k) {
        int j = nbr[base + k];
        const uint4 hv = *(const uint4*)(Ym + (size_t)j * ystride + c16 * 8);
        const float4 wa = *(const float4*)(wkL + k * 132 + c16 * 8);
        const float4 wb = *(const float4*)(wkL + k * 132 + c16 * 8 + 4);
        float h0 = fmaxf(0.f, hlo(hv.x) * aR[0] + cR[0]);
        float h1 = fmaxf(0.f, hhi(hv.x) * aR[1] + cR[1]);
        float h2 = fmaxf(0.f, hlo(hv.y) * aR[2] + cR[2]);
        float h3 = fmaxf(0.f, hhi(hv.y) * aR[3] + cR[3]);
        float h4 = fmaxf(0.f, hlo(hv.z) * aR[4] + cR[4]);
        float h5 = fmaxf(0.f, hhi(hv.z) * aR[5] + cR[5]);
        float h6 = fmaxf(0.f, hlo(hv.w) * aR[6] + cR[6]);
        float h7 = fmaxf(0.f, hhi(hv.w) * aR[7] + cR[7]);
        acc[0] += h0 * wa.x; acc[1] += h1 * wa.y;
        acc[2] += h2 * wa.z; acc[3] += h3 * wa.w;
        acc[4] += h4 * wb.x; acc[5] += h5 * wb.y;
        acc[6] += h6 * wb.z; acc[7] += h7 * wb.w;
    }

    float os[8], oq[8];
    if (alive) {
        float* p = P + (size_t)vox * 128 + c16 * 8;
        if (MODE == 0) {
            float4 v0 = {acc[0], acc[1], acc[2], acc[3]};
            float4 v1 = {acc[4], acc[5], acc[6], acc[7]};
            *(float4*)p = v0;
            *(float4*)(p + 4) = v1;
        } else {
            float4 o0 = *(const float4*)p, o1 = *(const float4*)(p + 4);
            o0.x += acc[0]; o0.y += acc[1]; o0.z += acc[2]; o0.w += acc[3];
            o1.x += acc[4]; o1.y += acc[5]; o1.z += acc[6]; o1.w += acc[7];
            *(float4*)p = o0;
            *(float4*)(p + 4) = o1;
            if (MODE == 2) {
                os[0] = o0.x; oq[0] = o0.x * o0.x;
                os[1] = o0.y; oq[1] = o0.y * o0.y;
                os[2] = o0.z; oq[2] = o0.z * o0.z;
                os[3] = o0.w; oq[3] = o0.w * o0.w;
                os[4] = o1.x; oq[4] = o1.x * o1.x;
                os[5] = o1.y; oq[5] = o1.y * o1.y;
                os[6] = o1.z; oq[6] = o1.z * o1.z;
                os[7] = o1.w; oq[7] = o1.w * o1.w;
            }
        }
    }
    if (MODE == 2) {
        if (!alive) {
#pragma unroll
            for (int e = 0; e < 8; ++e) { os[e] = 0.f; oq[e] = 0.f; }
        }
#pragma unroll
        for (int e = 0; e < 8; ++e) {
            os[e] += __shfl_xor(os[e], 16); os[e] += __shfl_xor(os[e], 32);
            oq[e] += __shfl_xor(oq[e], 16); oq[e] += __shfl_xor(oq[e], 32);
        }
        if (lane < 16) {
#pragma unroll
            for (int e = 0; e < 8; ++e) {
                atomicAdd(ssum + c16 * 8 + e, os[e]);
                atomicAdd(ssq  + c16 * 8 + e, oq[e]);
            }
        }
        __syncthreads();
        if (t < 128) {
            atomicAdd(osum + t, ssum[t]);
            atomicAdd(osq  + t, ssq[t]);
        }
    }
}

// --- K5: reduce output-stat bins, finalize output BN coefficients ---
__global__ void k5_coef(const float* __restrict__ osum_b, const float* __restrict__ osq_b,
                        int nbin,
                        const float* __restrict__ g, const float* __restrict__ b,
                        float* __restrict__ ao, float* __restrict__ co, int N) {
    int c = threadIdx.x;
    float s = 0.f, s2 = 0.f;
    for (int bi = 0; bi < nbin; ++bi) {
        s  += osum_b[bi * 128 + c];
        s2 += osq_b [bi * 128 + c];
    }
    float mean = s / (float)N;
    float var  = s2 / (float)N - mean * mean;
    float a = g[c] * rsqrtf(var + EPSV);
    ao[c] = a;
    co[c] = b[c] - mean * a;
}

// --- K6: out = relu(relu(P*a + c) + x), in-place on d_out ---
__launch_bounds__(256)
__global__ void k6_final(float* __restrict__ P, const float* __restrict__ x,
                         const float* __restrict__ ao, const float* __restrict__ co, int N) {
    long long t4 = ((long long)blockIdx.x * 256 + threadIdx.x) * 4;
    if (t4 >= (long long)N * 128) return;
    int c4 = (int)(t4 & 127);
    float4 p  = *(const float4*)(P + t4);
    float4 xv = *(const float4*)(x + t4);
    float4 a  = *(const float4*)(ao + c4);
    float4 c  = *(const float4*)(co + c4);
    float4 o;
    o.x = fmaxf(0.f, fmaxf(0.f, p.x * a.x + c.x) + xv.x);
    o.y = fmaxf(0.f, fmaxf(0.f, p.y * a.y + c.y) + xv.y);
    o.z = fmaxf(0.f, fmaxf(0.f, p.z * a.z + c.z) + xv.z);
    o.w = fmaxf(0.f, fmaxf(0.f, p.w * a.w + c.w) + xv.w);
    *(float4*)(P + t4) = o;
}

extern "C" void kernel_launch(void* const* d_in, const int* in_sizes, int n_in,
                              void* d_out, int out_size, void* d_ws, size_t ws_size,
                              hipStream_t stream) {
    const float* x     = (const float*)d_in[0];
    const int*   nbr   = (const int*)d_in[1];
    const float* W1    = (const float*)d_in[2];
    const float* g1    = (const float*)d_in[3];
    const float* b1    = (const float*)d_in[4];
    const float* wk    = (const float*)d_in[5];
    const float* g_out = (const float*)d_in[6];
    const float* b_out = (const float*)d_in[7];
    const int N = in_sizes[0] / 128;

    float* P = (float*)d_out;
    char* ws = (char*)d_ws;
    float* ysum = (float*)ws;          // [512]  (fallback only)
    float* ysq  = ysum + 512;          // [512]  (fallback only)
    float* osum = ysq + 512;           // [128]  (fallback only)
    float* osq  = osum + 128;          // [128]  (fallback only)
    float* osb  = osq + 128;           // [4*128] fused k4 output-stat bins
    float* oqb  = osb + 512;           // [4*128]
    float* a1   = oqb + 512;           // [512]
    float* c1   = a1 + 512;            // [512]
    float* ao   = c1 + 512;            // [128]
    float* co   = ao + 128;            // [128]
    float* colsum = co + 128;          // [128]
    unsigned short* WT = (unsigned short*)(ws + 16384);            // 4*128*128 bf16
    unsigned short* Y  = (unsigned short*)(ws + 16384 + 131072);   // Y buffer (f16, raw pre-BN)

    const bool fused = ws_size >= (size_t)16384 + 131072 + (size_t)N * 512 * 2;

    hipMemsetAsync(d_ws, 0, 16384, stream);
    k0_wt<<<512, 128, 0, stream>>>(W1, WT);

    const int gA = (N + 63) / 64;
    const int g4 = (N + 15) / 16;
    const int nchunk = (N + 63) / 64;

    if (fused) {
        // XtX partial slabs + final XtX live in dead P (front 8MB + 64KB)
        float* slabs = P;                         // [KS_NB][16384]
        float* XtXf  = P + (size_t)KS_NB * 16384; // [16384]
        kS_xtx<<<KS_NB, 256, 0, stream>>>(x, slabs, colsum, N, nchunk);
        kR_reduce<<<64, 256, 0, stream>>>(slabs, XtXf, KS_NB);
        k2b_coef<<<512, 256, 0, stream>>>(XtXf, colsum, W1, g1, b1, a1, c1, N);
        kA_gemm<0><<<gA, 256, 0, stream>>>(x, WT, Y, nullptr, nullptr, N, 0, 4, 512);
        k4_all<<<2048, 256, 0, stream>>>(Y, nbr, wk, a1, c1, P, osb, oqb, N);
        k5_coef<<<1, 128, 0, stream>>>(osb, oqb, 4, g_out, b_out, ao, co, N);
    } else {
        for (int m = 0; m < 4; ++m) {
            kA_gemm<1><<<gA, 256, 0, stream>>>(x, WT, Y, ysum, ysq, N, m, m + 1, 128);
            k2_coef<<<1, 128, 0, stream>>>(ysum, ysq, g1, b1, a1, c1, N, m);
            if (m == 0)
                k4_gather<0><<<g4, 256, 0, stream>>>(Y, 128, nbr, wk + m * KK * 128,
                                                     a1 + m * 128, c1 + m * 128, P, osum, osq, N);
            else if (m == 3)
                k4_gather<2><<<g4, 256, 0, stream>>>(Y, 128, nbr, wk + m * KK * 128,
                                                     a1 + m * 128, c1 + m * 128, P, osum, osq, N);
            else
                k4_gather<1><<<g4, 256, 0, stream>>>(Y, 128, nbr, wk + m * KK * 128,
                                                     a1 + m * 128, c1 + m * 128, P, osum, osq, N);
        }
        k5_coef<<<1, 128, 0, stream>>>(osum, osq, 1, g_out, b_out, ao, co, N);
    }
    const int g6 = (int)(((long long)N * 128 / 4 + 255) / 256);
    k6_final<<<g6, 256, 0, stream>>>(P, x, ao, co, N);
}

// Round 6
// 588.077 us; speedup vs baseline: 1.5868x; 1.5868x over previous
//
#include <hip/hip_runtime.h>

#define KK 27
#define EPSV 1e-5f

typedef __attribute__((ext_vector_type(8))) short bf16x8;
typedef __attribute__((ext_vector_type(4))) float f32x4;
typedef __attribute__((ext_vector_type(4))) unsigned int u32x4;

static __device__ __forceinline__ unsigned short f2bf(float f) {
    unsigned u = __float_as_uint(f);
    u = u + 0x7fffu + ((u >> 16) & 1u);
    return (unsigned short)(u >> 16);
}

// f16 helpers (v_cvt_f16_f32 / v_cvt_f32_f16, SDWA hi/lo selects fold the shift)
static __device__ __forceinline__ unsigned short f2h(float f) {
    _Float16 h = (_Float16)f;
    unsigned short u;
    __builtin_memcpy(&u, &h, 2);
    return u;
}
static __device__ __forceinline__ float h2f(unsigned short s) {
    _Float16 h;
    __builtin_memcpy(&h, &s, 2);
    return (float)h;
}
static __device__ __forceinline__ float hlo(unsigned u) { return h2f((unsigned short)(u & 0xffffu)); }
static __device__ __forceinline__ float hhi(unsigned u) { return h2f((unsigned short)(u >> 16)); }

// --- K0: transpose+convert W1[m][k][n] (fp32) -> WT[m][n][k] (bf16) via LDS tile.
//     Old version read W1 at stride 512B (128 lines/wave-load, ~16x over-fetch).
//     Now: coalesced 64B-segment reads, fully coalesced 256B writes. 32 blocks.
__global__ void k0_wt(const float* __restrict__ W1, unsigned short* __restrict__ WT) {
    __shared__ unsigned short tile[128 * 18];   // [k][n], pad 18 shorts
    const int m = blockIdx.x >> 3, n0 = (blockIdx.x & 7) * 16;
    const int t = threadIdx.x;
    const int kin = t >> 4, nin = t & 15;
#pragma unroll
    for (int it = 0; it < 8; ++it) {
        int k = it * 16 + kin;
        tile[k * 18 + nin] = f2bf(W1[((size_t)(m * 128 + k) * 128) + n0 + nin]);
    }
    __syncthreads();
    const int w = t >> 6, ko = (t & 63) * 2;
#pragma unroll
    for (int it = 0; it < 4; ++it) {
        int n = it * 4 + w;
        ushort2 v;
        v.x = tile[ko * 18 + n];
        v.y = tile[(ko + 1) * 18 + n];
        *(ushort2*)(WT + (size_t)(m * 128 + n0 + n) * 128 + ko) = v;
    }
}

// --- KA: y_m = x @ W1[m] for m in [m0,m1); Yall[row][(m-m0)*128 + c] f16 raw (pre-BN)
//     Stats binned: ysum_b/ysq_b[bin*binstride + m*128+col], bin = blockIdx & binmask
//     (binning kills same-line atomic serialization: 3.2M atomics / 4KB otherwise).
__launch_bounds__(256)
__global__ void kA_gemm(const float* __restrict__ x, const unsigned short* __restrict__ WT,
                        unsigned short* __restrict__ Yall, float* __restrict__ ysum_b,
                        float* __restrict__ ysq_b, int binstride, int binmask,
                        int N, int m0, int m1, int ystride) {
    __shared__ unsigned short As[64 * 136];   // [row][k], pad 8
    __shared__ unsigned short Bs[128 * 136];  // [n][k], pad 8; reused as Ys tile per m
    const int t = threadIdx.x;
    const int i0 = blockIdx.x * 64;
    const int binoff = (blockIdx.x & binmask) * binstride;

#pragma unroll
    for (int it = 0; it < 8; ++it) {
        int flat = it * 256 + t;
        int r = flat >> 5, c4 = (flat & 31) * 4;
        float4 v = make_float4(0.f, 0.f, 0.f, 0.f);
        if (i0 + r < N) v = *(const float4*)(x + (size_t)(i0 + r) * 128 + c4);
        ushort4 bb;
        bb.x = f2bf(v.x); bb.y = f2bf(v.y); bb.z = f2bf(v.z); bb.w = f2bf(v.w);
        *(ushort4*)(As + r * 136 + c4) = bb;
    }

    const int w = t >> 6, lane = t & 63;
    const int wr = w >> 1, wc = w & 1;
    const int r16 = lane & 15, q = lane >> 4;

    for (int m = m0; m < m1; ++m) {
        __syncthreads();
        const uint4* Wp = (const uint4*)(WT + (size_t)m * 128 * 128);
#pragma unroll
        for (int it = 0; it < 8; ++it) {
            int flat = it * 256 + t;
            int n = flat >> 4, kc = flat & 15;
            uint4 v = Wp[n * 16 + kc];
            *(uint4*)(Bs + n * 136 + kc * 8) = v;
        }
        __syncthreads();

        f32x4 acc[2][4];
#pragma unroll
        for (int a = 0; a < 2; ++a)
#pragma unroll
            for (int b = 0; b < 4; ++b) { acc[a][b][0] = 0.f; acc[a][b][1] = 0.f; acc[a][b][2] = 0.f; acc[a][b][3] = 0.f; }

#pragma unroll
        for (int ks = 0; ks < 4; ++ks) {
            int ko = ks * 32 + q * 8;
            bf16x8 af[2], bfr[4];
#pragma unroll
            for (int ri = 0; ri < 2; ++ri)
                af[ri] = *(const bf16x8*)(As + (wr * 32 + ri * 16 + r16) * 136 + ko);
#pragma unroll
            for (int ci = 0; ci < 4; ++ci)
                bfr[ci] = *(const bf16x8*)(Bs + (wc * 64 + ci * 16 + r16) * 136 + ko);
#pragma unroll
            for (int ri = 0; ri < 2; ++ri)
#pragma unroll
                for (int ci = 0; ci < 4; ++ci)
                    acc[ri][ci] = __builtin_amdgcn_mfma_f32_16x16x32_bf16(af[ri], bfr[ci], acc[ri][ci], 0, 0, 0);
        }

#pragma unroll
        for (int ci = 0; ci < 4; ++ci) {
            float s = 0.f, s2 = 0.f;
#pragma unroll
            for (int ri = 0; ri < 2; ++ri) {
#pragma unroll
                for (int r = 0; r < 4; ++r) {
                    int row = i0 + wr * 32 + ri * 16 + q * 4 + r;
                    float vv = acc[ri][ci][r];
                    if (row < N) { s += vv; s2 += vv * vv; }
                }
            }
            s  += __shfl_xor(s, 16);  s  += __shfl_xor(s, 32);
            s2 += __shfl_xor(s2, 16); s2 += __shfl_xor(s2, 32);
            if (lane < 16) {
                int col = wc * 64 + ci * 16 + r16;
                atomicAdd(ysum_b + binoff + m * 128 + col, s);
                atomicAdd(ysq_b  + binoff + m * 128 + col, s2);
            }
        }

        __syncthreads();
        unsigned short* Ys = Bs;
#pragma unroll
        for (int ci = 0; ci < 4; ++ci) {
            int col = wc * 64 + ci * 16 + r16;
#pragma unroll
            for (int ri = 0; ri < 2; ++ri) {
#pragma unroll
                for (int r = 0; r < 4; ++r) {
                    int rl = wr * 32 + ri * 16 + q * 4 + r;
                    Ys[rl * 136 + col] = f2h(acc[ri][ci][r]);
                }
            }
        }
        __syncthreads();
        const int cb = (m - m0) * 128;
#pragma unroll
        for (int it = 0; it < 4; ++it) {
            int chunk = it * 256 + t;
            int row = chunk >> 4, c8 = (chunk & 15) * 8;
            if (i0 + row < N) {
                u32x4 v = *(const u32x4*)(Ys + row * 136 + c8);
                __builtin_nontemporal_store(v, (u32x4*)(Yall + (size_t)(i0 + row) * ystride + cb + c8));
            }
        }
    }
}

// --- K2 (binned): reduce stat bins, finalize BN1 coefficients. total threads = 512 ---
__global__ void k2_coef_b(const float* __restrict__ ysum_b, const float* __restrict__ ysq_b,
                          int nbin, int binstride,
                          const float* __restrict__ g1, const float* __restrict__ b1,
                          float* __restrict__ a1, float* __restrict__ c1, int N) {
    int idx = blockIdx.x * blockDim.x + threadIdx.x;   // = m*128+c
    float s = 0.f, s2 = 0.f;
    for (int b = 0; b < nbin; ++b) {
        s  += ysum_b[b * binstride + idx];
        s2 += ysq_b [b * binstride + idx];
    }
    float mean = s / (float)N;
    float var  = s2 / (float)N - mean * mean;
    float a = g1[idx] * rsqrtf(var + EPSV);
    a1[idx] = a;
    c1[idx] = b1[idx] - mean * a;
}

// --- K2 (fallback single-bin) ---
__global__ void k2_coef(const float* __restrict__ ysum, const float* __restrict__ ysq,
                        const float* __restrict__ g1, const float* __restrict__ b1,
                        float* __restrict__ a1, float* __restrict__ c1, int N, int m0) {
    int c = threadIdx.x & 127;
    int m = m0 + (threadIdx.x >> 7);
    float mean = ysum[m * 128 + c] / (float)N;
    float var  = ysq[m * 128 + c] / (float)N - mean * mean;
    float a = g1[m * 128 + c] * rsqrtf(var + EPSV);
    a1[m * 128 + c] = a;
    c1[m * 128 + c] = b1[m * 128 + c] - mean * a;
}

// --- K4_ALL: gather with inline BN+ReLU. 4 voxels per wave (quad q owns v0+q).
//     Grid 2048 (empirically best across R0-R5; 1280 "exact residency" regressed).
//     Output stats binned 4x. This kernel is pinned at the random-gather memory
//     system ceiling (~7 TB/s delivered); three different inner loops all ~395us.
__launch_bounds__(256)
__global__ void k4_all(const unsigned short* __restrict__ Y, const int* __restrict__ nbr,
                       const float* __restrict__ wkg, const float* __restrict__ A1g,
                       const float* __restrict__ C1g, float* __restrict__ P,
                       float* __restrict__ osum_b, float* __restrict__ osq_b, int N) {
    __shared__ unsigned short wkL[4 * KK * 136];   // f16 [m*27+k][c] pad 8
    __shared__ float ssum[128], ssq[128];
    const int t = threadIdx.x;
    for (int idx = t; idx < 4 * KK * 128; idx += 256) {
        int c = idx & 127, km = idx >> 7;          // km = m*27+k (c inner)
        wkL[km * 136 + c] = f2h(wkg[idx]);
    }
    if (t < 128) { ssum[t] = 0.f; ssq[t] = 0.f; }

    const int lane = t & 63;
    const int m = lane >> 4, c16 = lane & 15;
    const int q = m;
    const unsigned short* wbase = wkL + (m * KK) * 136 + c16 * 8;
    const unsigned short* hbase = Y + lane * 8;

    // BN coefficients for THIS lane's branch m, channels c16*8..+8
    float Ar[8], Cr[8];
    {
        const float4 A0 = *(const float4*)(A1g + m * 128 + c16 * 8);
        const float4 A1 = *(const float4*)(A1g + m * 128 + c16 * 8 + 4);
        const float4 C0 = *(const float4*)(C1g + m * 128 + c16 * 8);
        const float4 C1 = *(const float4*)(C1g + m * 128 + c16 * 8 + 4);
        Ar[0]=A0.x; Ar[1]=A0.y; Ar[2]=A0.z; Ar[3]=A0.w;
        Ar[4]=A1.x; Ar[5]=A1.y; Ar[6]=A1.z; Ar[7]=A1.w;
        Cr[0]=C0.x; Cr[1]=C0.y; Cr[2]=C0.z; Cr[3]=C0.w;
        Cr[4]=C1.x; Cr[5]=C1.y; Cr[6]=C1.z; Cr[7]=C1.w;
    }
    __syncthreads();

    float os[8], oq[8];
#pragma unroll
    for (int e = 0; e < 8; ++e) { os[e] = 0.f; oq[e] = 0.f; }

    const int wid = blockIdx.x * 4 + (t >> 6);
    const int nw  = gridDim.x * 4;
    const int ng  = (N + 3) >> 2;
    for (int vg = wid; vg < ng; vg += nw) {
        const int v0 = __builtin_amdgcn_readfirstlane(vg << 2);
        const int* np = nbr + (size_t)v0 * KK;     // wave-uniform -> s_load
        const int o1 = (v0 + 1 < N) ? KK : 0;      // clamp tail rows (replay row 0)
        const int o2 = (v0 + 2 < N) ? 2 * KK : 0;
        const int o3 = (v0 + 3 < N) ? 3 * KK : 0;
        float acc0[8], acc1[8], acc2[8], acc3[8];
#pragma unroll
        for (int e = 0; e < 8; ++e) { acc0[e] = 0.f; acc1[e] = 0.f; acc2[e] = 0.f; acc3[e] = 0.f; }

#pragma unroll 3
        for (int k = 0; k < KK; ++k) {
            const int j0 = np[k];
            const int j1 = np[o1 + k];
            const int j2 = np[o2 + k];
            const int j3 = np[o3 + k];
            // whole wave loads each full 1KB interleaved row: lane*16B
            const uint4 hv0 = *(const uint4*)(hbase + ((size_t)j0 << 9));
            const uint4 hv1 = *(const uint4*)(hbase + ((size_t)j1 << 9));
            const uint4 hv2 = *(const uint4*)(hbase + ((size_t)j2 << 9));
            const uint4 hv3 = *(const uint4*)(hbase + ((size_t)j3 << 9));
            const uint4 wv  = *(const uint4*)(wbase + k * 136);
            const float w0 = hlo(wv.x), w1 = hhi(wv.x), w2 = hlo(wv.y), w3 = hhi(wv.y);
            const float w4 = hlo(wv.z), w5 = hhi(wv.z), w6 = hlo(wv.w), w7 = hhi(wv.w);
#define K4BODY(A, H)                                                        \
            A[0] += fmaxf(0.f, hlo(H.x) * Ar[0] + Cr[0]) * w0;              \
            A[1] += fmaxf(0.f, hhi(H.x) * Ar[1] + Cr[1]) * w1;              \
            A[2] += fmaxf(0.f, hlo(H.y) * Ar[2] + Cr[2]) * w2;              \
            A[3] += fmaxf(0.f, hhi(H.y) * Ar[3] + Cr[3]) * w3;              \
            A[4] += fmaxf(0.f, hlo(H.z) * Ar[4] + Cr[4]) * w4;              \
            A[5] += fmaxf(0.f, hhi(H.z) * Ar[5] + Cr[5]) * w5;              \
            A[6] += fmaxf(0.f, hlo(H.w) * Ar[6] + Cr[6]) * w6;              \
            A[7] += fmaxf(0.f, hhi(H.w) * Ar[7] + Cr[7]) * w7;
            K4BODY(acc0, hv0)
            K4BODY(acc1, hv1)
            K4BODY(acc2, hv2)
            K4BODY(acc3, hv3)
#undef K4BODY
        }

        // sum over the 4 branches (quads): lanes {l, l^16, l^32, l^48}
#pragma unroll
        for (int e = 0; e < 8; ++e) {
            acc0[e] += __shfl_xor(acc0[e], 16); acc0[e] += __shfl_xor(acc0[e], 32);
            acc1[e] += __shfl_xor(acc1[e], 16); acc1[e] += __shfl_xor(acc1[e], 32);
            acc2[e] += __shfl_xor(acc2[e], 16); acc2[e] += __shfl_xor(acc2[e], 32);
            acc3[e] += __shfl_xor(acc3[e], 16); acc3[e] += __shfl_xor(acc3[e], 32);
        }
        // quad q owns voxel v0+q (static select — no runtime array index)
        float av[8];
#pragma unroll
        for (int e = 0; e < 8; ++e)
            av[e] = (q == 0) ? acc0[e] : (q == 1) ? acc1[e] : (q == 2) ? acc2[e] : acc3[e];
        const int vq = v0 + q;
        if (vq < N) {
            f32x4 x0 = {av[0], av[1], av[2], av[3]};
            f32x4 x1 = {av[4], av[5], av[6], av[7]};
            float* p = P + (size_t)vq * 128 + c16 * 8;
            __builtin_nontemporal_store(x0, (f32x4*)p);
            __builtin_nontemporal_store(x1, (f32x4*)(p + 4));
#pragma unroll
            for (int e = 0; e < 8; ++e) { os[e] += av[e]; oq[e] += av[e] * av[e]; }
        }
    }

    // every lane contributes its quad's voxel stats (LDS pre-reduce, then binned global)
#pragma unroll
    for (int e = 0; e < 8; ++e) {
        atomicAdd(ssum + c16 * 8 + e, os[e]);
        atomicAdd(ssq  + c16 * 8 + e, oq[e]);
    }
    __syncthreads();
    if (t < 128) {
        const int bo = (blockIdx.x & 3) * 128;
        atomicAdd(osum_b + bo + t, ssum[t]);
        atomicAdd(osq_b  + bo + t, ssq[t]);
    }
}

// --- K4 fallback (per-branch, compact Y, BN inline; Y is f16) ---
template <int MODE>
__launch_bounds__(256)
__global__ void k4_gather(const unsigned short* __restrict__ Ym, int ystride,
                          const int* __restrict__ nbr,
                          const float* __restrict__ wkm, const float* __restrict__ a1m,
                          const float* __restrict__ c1m, float* __restrict__ P,
                          float* __restrict__ osum, float* __restrict__ osq, int N) {
    __shared__ float wkL[KK * 132];
    __shared__ float ssum[128], ssq[128];
    const int t = threadIdx.x;
    for (int idx = t; idx < KK * 128; idx += 256) {
        int k = idx >> 7, c = idx & 127;
        wkL[k * 132 + c] = wkm[k * 128 + c];
    }
    if (MODE == 2) { if (t < 128) { ssum[t] = 0.f; ssq[t] = 0.f; } }

    const int w = t >> 6, lane = t & 63;
    const int q = lane >> 4, c16 = lane & 15;
    const int slot = w * 4 + q;
    const int vox = blockIdx.x * 16 + slot;
    const bool alive = vox < N;

    float aR[8], cR[8];
    {
        const float4 A0 = *(const float4*)(a1m + c16 * 8);
        const float4 A1 = *(const float4*)(a1m + c16 * 8 + 4);
        const float4 C0 = *(const float4*)(c1m + c16 * 8);
        const float4 C1 = *(const float4*)(c1m + c16 * 8 + 4);
        aR[0]=A0.x; aR[1]=A0.y; aR[2]=A0.z; aR[3]=A0.w;
        aR[4]=A1.x; aR[5]=A1.y; aR[6]=A1.z; aR[7]=A1.w;
        cR[0]=C0.x; cR[1]=C0.y; cR[2]=C0.z; cR[3]=C0.w;
        cR[4]=C1.x; cR[5]=C1.y; cR[6]=C1.z; cR[7]=C1.w;
    }
    __syncthreads();

    const long long base = alive ? (long long)vox * KK : 0;
    float acc[8];
#pragma unroll
    for (int e = 0; e < 8; ++e) acc[e] = 0.f;

#pragma unroll 3
    for (int k = 0; k < KK; ++k) {
        int j = nbr[base + k];
        const uint4 hv = *(const uint4*)(Ym + (size_t)j * ystride + c16 * 8);
        const float4 wa = *(const float4*)(wkL + k * 132 + c16 * 8);
        const float4 wb = *(const float4*)(wkL + k * 132 + c16 * 8 + 4);
        float h0 = fmaxf(0.f, hlo(hv.x) * aR[0] + cR[0]);
        float h1 = fmaxf(0.f, hhi(hv.x) * aR[1] + cR[1]);
        float h2 = fmaxf(0.f, hlo(hv.y) * aR[2] + cR[2]);
        float h3 = fmaxf(0.f, hhi(hv.y) * aR[3] + cR[3]);
        float h4 = fmaxf(0.f, hlo(hv.z) * aR[4] + cR[4]);
        float h5 = fmaxf(0.f, hhi(hv.z) * aR[5] + cR[5]);
        float h6 = fmaxf(0.f, hlo(hv.w) * aR[6] + cR[6]);
        float h7 = fmaxf(0.f, hhi(hv.w) * aR[7] + cR[7]);
        acc[0] += h0 * wa.x; acc[1] += h1 * wa.y;
        acc[2] += h2 * wa.z; acc[3] += h3 * wa.w;
        acc[4] += h4 * wb.x; acc[5] += h5 * wb.y;
        acc[6] += h6 * wb.z; acc[7] += h7 * wb.w;
    }

    float os[8], oq[8];
    if (alive) {
        float* p = P + (size_t)vox * 128 + c16 * 8;
        if (MODE == 0) {
            float4 v0 = {acc[0], acc[1], acc[2], acc[3]};
            float4 v1 = {acc[4], acc[5], acc[6], acc[7]};
            *(float4*)p = v0;
            *(float4*)(p + 4) = v1;
        } else {
            float4 o0 = *(const float4*)p, o1 = *(const float4*)(p + 4);
            o0.x += acc[0]; o0.y += acc[1]; o0.z += acc[2]; o0.w += acc[3];
            o1.x += acc[4]; o1.y += acc[5]; o1.z += acc[6]; o1.w += acc[7];
            *(float4*)p = o0;
            *(float4*)(p + 4) = o1;
            if (MODE == 2) {
                os[0] = o0.x; oq[0] = o0.x * o0.x;
                os[1] = o0.y; oq[1] = o0.y * o0.y;
                os[2] = o0.z; oq[2] = o0.z * o0.z;
                os[3] = o0.w; oq[3] = o0.w * o0.w;
                os[4] = o1.x; oq[4] = o1.x * o1.x;
                os[5] = o1.y; oq[5] = o1.y * o1.y;
                os[6] = o1.z; oq[6] = o1.z * o1.z;
                os[7] = o1.w; oq[7] = o1.w * o1.w;
            }
        }
    }
    if (MODE == 2) {
        if (!alive) {
#pragma unroll
            for (int e = 0; e < 8; ++e) { os[e] = 0.f; oq[e] = 0.f; }
        }
#pragma unroll
        for (int e = 0; e < 8; ++e) {
            os[e] += __shfl_xor(os[e], 16); os[e] += __shfl_xor(os[e], 32);
            oq[e] += __shfl_xor(oq[e], 16); oq[e] += __shfl_xor(oq[e], 32);
        }
        if (lane < 16) {
#pragma unroll
            for (int e = 0; e < 8; ++e) {
                atomicAdd(ssum + c16 * 8 + e, os[e]);
                atomicAdd(ssq  + c16 * 8 + e, oq[e]);
            }
        }
        __syncthreads();
        if (t < 128) {
            atomicAdd(osum + t, ssum[t]);
            atomicAdd(osq  + t, ssq[t]);
        }
    }
}

// --- K5: reduce output-stat bins, finalize output BN coefficients ---
__global__ void k5_coef(const float* __restrict__ osum_b, const float* __restrict__ osq_b,
                        int nbin,
                        const float* __restrict__ g, const float* __restrict__ b,
                        float* __restrict__ ao, float* __restrict__ co, int N) {
    int c = threadIdx.x;
    float s = 0.f, s2 = 0.f;
    for (int bi = 0; bi < nbin; ++bi) {
        s  += osum_b[bi * 128 + c];
        s2 += osq_b [bi * 128 + c];
    }
    float mean = s / (float)N;
    float var  = s2 / (float)N - mean * mean;
    float a = g[c] * rsqrtf(var + EPSV);
    ao[c] = a;
    co[c] = b[c] - mean * a;
}

// --- K6: out = relu(relu(P*a + c) + x), in-place on d_out ---
__launch_bounds__(256)
__global__ void k6_final(float* __restrict__ P, const float* __restrict__ x,
                         const float* __restrict__ ao, const float* __restrict__ co, int N) {
    long long t4 = ((long long)blockIdx.x * 256 + threadIdx.x) * 4;
    if (t4 >= (long long)N * 128) return;
    int c4 = (int)(t4 & 127);
    float4 p  = *(const float4*)(P + t4);
    float4 xv = *(const float4*)(x + t4);
    float4 a  = *(const float4*)(ao + c4);
    float4 c  = *(const float4*)(co + c4);
    float4 o;
    o.x = fmaxf(0.f, fmaxf(0.f, p.x * a.x + c.x) + xv.x);
    o.y = fmaxf(0.f, fmaxf(0.f, p.y * a.y + c.y) + xv.y);
    o.z = fmaxf(0.f, fmaxf(0.f, p.z * a.z + c.z) + xv.z);
    o.w = fmaxf(0.f, fmaxf(0.f, p.w * a.w + c.w) + xv.w);
    *(float4*)(P + t4) = o;
}

extern "C" void kernel_launch(void* const* d_in, const int* in_sizes, int n_in,
                              void* d_out, int out_size, void* d_ws, size_t ws_size,
                              hipStream_t stream) {
    const float* x     = (const float*)d_in[0];
    const int*   nbr   = (const int*)d_in[1];
    const float* W1    = (const float*)d_in[2];
    const float* g1    = (const float*)d_in[3];
    const float* b1    = (const float*)d_in[4];
    const float* wk    = (const float*)d_in[5];
    const float* g_out = (const float*)d_in[6];
    const float* b_out = (const float*)d_in[7];
    const int N = in_sizes[0] / 128;

    float* P = (float*)d_out;
    char* ws = (char*)d_ws;
    float* ysum = (float*)ws;          // [512]  (fallback only)
    float* ysq  = ysum + 512;          // [512]  (fallback only)
    float* osum = ysq + 512;           // [128]  (fallback only)
    float* osq  = osum + 128;          // [128]  (fallback only)
    float* osb  = osq + 128;           // [4*128] fused k4 output-stat bins
    float* oqb  = osb + 512;           // [4*128]
    float* a1   = oqb + 512;           // [512]
    float* c1   = a1 + 512;            // [512]
    float* ao   = c1 + 512;            // [128]
    float* co   = ao + 128;            // [128]
    unsigned short* WT = (unsigned short*)(ws + 16384);            // 4*128*128 bf16
    unsigned short* Y  = (unsigned short*)(ws + 16384 + 131072);   // Y buffer (f16, raw pre-BN)

    const bool fused = ws_size >= (size_t)16384 + 131072 + (size_t)N * 512 * 2;

    hipMemsetAsync(d_ws, 0, 16384, stream);
    k0_wt<<<32, 256, 0, stream>>>(W1, WT);

    const int gA = (N + 63) / 64;
    const int g4 = (N + 15) / 16;

    if (fused) {
        // kA stat bins live in the first 256KB of P (dead until k4 overwrites it)
        float* ysum_b = P;             // [64][512]
        float* ysq_b  = P + 64 * 512;  // [64][512]
        hipMemsetAsync(d_out, 0, 64 * 512 * 2 * sizeof(float), stream);
        kA_gemm<<<gA, 256, 0, stream>>>(x, WT, Y, ysum_b, ysq_b, 512, 63, N, 0, 4, 512);
        k2_coef_b<<<2, 256, 0, stream>>>(ysum_b, ysq_b, 64, 512, g1, b1, a1, c1, N);
        k4_all<<<2048, 256, 0, stream>>>(Y, nbr, wk, a1, c1, P, osb, oqb, N);
        k5_coef<<<1, 128, 0, stream>>>(osb, oqb, 4, g_out, b_out, ao, co, N);
    } else {
        for (int m = 0; m < 4; ++m) {
            kA_gemm<<<gA, 256, 0, stream>>>(x, WT, Y, ysum, ysq, 0, 0, N, m, m + 1, 128);
            k2_coef<<<1, 128, 0, stream>>>(ysum, ysq, g1, b1, a1, c1, N, m);
            if (m == 0)
                k4_gather<0><<<g4, 256, 0, stream>>>(Y, 128, nbr, wk + m * KK * 128,
                                                     a1 + m * 128, c1 + m * 128, P, osum, osq, N);
            else if (m == 3)
                k4_gather<2><<<g4, 256, 0, stream>>>(Y, 128, nbr, wk + m * KK * 128,
                                                     a1 + m * 128, c1 + m * 128, P, osum, osq, N);
            else
                k4_gather<1><<<g4, 256, 0, stream>>>(Y, 128, nbr, wk + m * KK * 128,
                                                     a1 + m * 128, c1 + m * 128, P, osum, osq, N);
        }
        k5_coef<<<1, 128, 0, stream>>>(osum, osq, 1, g_out, b_out, ao, co, N);
    }
    const int g6 = (int)(((long long)N * 128 / 4 + 255) / 256);
    k6_final<<<g6, 256, 0, stream>>>(P, x, ao, co, N);
}